// Round 11
// baseline (153.268 us; speedup 1.0000x reference)
//
#include <hip/hip_runtime.h>
#include <hip/hip_bf16.h>

#define B_    8
#define DIM_  256
#define NH_   8
#define HD_   32
#define KD_   16
#define HOUT_ 512
#define N_    1024
#define SCALE_ 0.25f
#define EPS_  1e-3f

typedef unsigned short u16;
typedef unsigned int   u32;
typedef __attribute__((ext_vector_type(8)))  short short8;   // 8 bf16 (4 VGPR)
typedef __attribute__((ext_vector_type(4)))  float f32x4;
typedef __attribute__((ext_vector_type(16))) float f32x16;

union H4 { uint2 u; u16 e[4]; };
union FragU { uint4 u; short8 s; };
union F8 { short8 s; u16 e[8]; };

__device__ __forceinline__ float b2f(u16 u) {
    union { unsigned int i; float f; } c;
    c.i = ((unsigned int)u) << 16;
    return c.f;
}

__device__ __forceinline__ u16 f2b(float f) {
    union { float f; unsigned int i; } c;
    c.f = f;
    unsigned int x = c.i;
    return (u16)((x + 0x7fffu + ((x >> 16) & 1u)) >> 16);  // RNE
}

// 8 contiguous fp32 -> bf16 frag
__device__ __forceinline__ short8 cvt8(const float* p) {
    float4 a = ((const float4*)p)[0];
    float4 b = ((const float4*)p)[1];
    F8 f;
    f.e[0] = f2b(a.x); f.e[1] = f2b(a.y); f.e[2] = f2b(a.z); f.e[3] = f2b(a.w);
    f.e[4] = f2b(b.x); f.e[5] = f2b(b.y); f.e[6] = f2b(b.z); f.e[7] = f2b(b.w);
    return f.s;
}

// 8 stride-N fp32 -> bf16 frag
__device__ __forceinline__ short8 cvt8s(const float* p) {
    F8 f;
    #pragma unroll
    for (int j = 0; j < 8; ++j) f.e[j] = f2b(p[(size_t)j * N_]);
    return f.s;
}

// ============ Kernel 1: qkv = BN(qkv_w @ x) -> bf16 [o][n], MFMA ============
// No prep kernel: BN folded in a 64-thread prologue (q channels get SCALE
// folded in — exact x0.25), fp32 weights converted to bf16 frags on the fly,
// B-frags assembled from fp32 x via strided dwords + cvt.
// Block 64o x 128n (block ob == head ob), 4 waves. grid = 8b x 8ob x 8nb = 512.
__global__ __launch_bounds__(256) void k_qkv(
    const float* __restrict__ x, const float* __restrict__ qw,
    const float* __restrict__ qg, const float* __restrict__ qb,
    const float* __restrict__ qm, const float* __restrict__ qv,
    u16* __restrict__ qkv)
{
    __shared__ float2 bn_s[64];
    int blk = blockIdx.x;
    int nb = blk & 7, ob = (blk >> 3) & 7, b = blk >> 6;
    int t = threadIdx.x;
    int wv_ = t >> 6, lane = t & 63, quad = lane >> 4, l16 = lane & 15;
    int o_base = ob * 64 + (wv_ & 1) * 32;
    int n_base = nb * 128 + (wv_ >> 1) * 64;

    if (t < 64) {
        int o = ob * 64 + t;
        float inv  = qg[o] / sqrtf(qv[o] + EPS_);
        float beta = qb[o] - qm[o] * inv;
        if (t < 16) { inv *= SCALE_; beta *= SCALE_; }   // q channels pre-scaled
        bn_s[t] = make_float2(inv, beta);
    }
    __syncthreads();

    f32x4 acc[2][4];
    #pragma unroll
    for (int ot = 0; ot < 2; ++ot)
        #pragma unroll
        for (int nt = 0; nt < 4; ++nt) acc[ot][nt] = (f32x4){0.f, 0.f, 0.f, 0.f};

    const float* xb = x + (size_t)b * DIM_ * N_;
    for (int c0 = 0; c0 < DIM_; c0 += 32) {
        short8 af[2];
        #pragma unroll
        for (int ot = 0; ot < 2; ++ot)
            af[ot] = cvt8(qw + (size_t)(o_base + ot * 16 + l16) * DIM_ + c0 + quad * 8);
        short8 bf[4];
        #pragma unroll
        for (int nt = 0; nt < 4; ++nt)
            bf[nt] = cvt8s(xb + (size_t)(c0 + quad * 8) * N_ + n_base + nt * 16 + l16);
        #pragma unroll
        for (int ot = 0; ot < 2; ++ot)
            #pragma unroll
            for (int nt = 0; nt < 4; ++nt)
                acc[ot][nt] = __builtin_amdgcn_mfma_f32_16x16x32_bf16(af[ot], bf[nt], acc[ot][nt], 0, 0, 0);
    }
    #pragma unroll
    for (int ot = 0; ot < 2; ++ot)
        #pragma unroll
        for (int r = 0; r < 4; ++r) {
            int ol = (wv_ & 1) * 32 + ot * 16 + quad * 4 + r;
            float2 ib = bn_s[ol];
            u16* dst = qkv + (size_t)(b * HOUT_ + ob * 64 + ol) * N_ + n_base + l16;
            #pragma unroll
            for (int nt = 0; nt < 4; ++nt)
                dst[nt * 16] = f2b(acc[ot][nt][r] * ib.x + ib.y);
        }
}

// ============ Kernel 2: flash attention, 32x32x16 MFMA, register-P, key-split ============
// R10-verified structure. Per block: 64 q. Waves (kh=wv>>1, qt=wv&1).
// S^T = mfma_32x32x16(K, Q') (q pre-scaled in k_qkv); shfl_xor(32) pair
// exchange -> PV B-operand; PV A=V b128 global. pe taps BN-folded in prologue.
struct MainS { u16 q_t[64][24]; u16 k_t[2][256][24]; };
struct EpiS  { u16 o_acc[2][32][66]; float l_s[2][64]; float v_pe[128][33]; };
union  SmemU { MainS m; EpiS e; };

__global__ __launch_bounds__(256) void k_attn(
    const u16* __restrict__ qkv, const float* __restrict__ pew,
    const float* __restrict__ eg, const float* __restrict__ eb,
    const float* __restrict__ em, const float* __restrict__ ev,
    u16* __restrict__ xattnT)
{
    __shared__ SmemU su;
    __shared__ float wpe_s[32][10];   // 9 folded taps + beta, live whole kernel
    int blk = blockIdx.x;
    int qb = blk & 15;
    int h  = (blk >> 4) & 7;
    int b  = blk >> 7;
    int t    = threadIdx.x;
    int wv_  = t >> 6;
    int lane = t & 63;
    int q5   = lane & 31;
    int hw   = lane >> 5;
    int kh   = wv_ >> 1;
    int qt   = wv_ & 1;
    const u16* base = qkv + (size_t)(b * HOUT_ + h * 64) * N_;  // q':d, k:16+d, v:32+d
    int q0g = qb * 64;

    if (t < 32) {   // fold pe BN into taps
        int c = h * 32 + t;
        float inv = eg[c] / sqrtf(ev[c] + EPS_);
        #pragma unroll
        for (int k = 0; k < 9; ++k) wpe_s[t][k] = pew[c * 9 + k] * inv;
        wpe_s[t][9] = eb[c] - em[c] * inv;
    }
    {   // stage 64 q transposed (pure u16 copy — scale pre-folded)
        int q = t & 63, d4 = (t >> 6) * 4;
        H4 hh;
        #pragma unroll
        for (int i = 0; i < 4; ++i)
            hh.e[i] = base[(size_t)(d4 + i) * N_ + q0g + q];
        *(uint2*)&su.m.q_t[q][d4] = hh.u;
    }
    __syncthreads();

    short8 qf = *(const short8*)&su.m.q_t[qt * 32 + q5][hw * 8];

    f32x16 oacc = {0.f,0.f,0.f,0.f, 0.f,0.f,0.f,0.f, 0.f,0.f,0.f,0.f, 0.f,0.f,0.f,0.f};
    float l_lane = 0.f;

    for (int ch = 0; ch < 2; ++ch) {
        __syncthreads();
        {   // stage 512 keys (both halves), lane = key, conflict-free
            #pragma unroll
            for (int s2 = 0; s2 < 2; ++s2) {
                int key = s2 * 512 + ch * 256 + t;
                #pragma unroll
                for (int d4 = 0; d4 < 16; d4 += 4) {
                    H4 hh;
                    #pragma unroll
                    for (int i = 0; i < 4; ++i)
                        hh.e[i] = base[(size_t)(16 + d4 + i) * N_ + key];
                    *(uint2*)&su.m.k_t[s2][t][d4] = hh.u;
                }
            }
        }
        __syncthreads();

        #pragma unroll 2
        for (int tile = 0; tile < 8; ++tile) {
            int key0 = kh * 512 + ch * 256 + tile * 32;
            short8 kf = *(const short8*)&su.m.k_t[kh][tile * 32 + q5][hw * 8];
            f32x16 z = {0.f,0.f,0.f,0.f, 0.f,0.f,0.f,0.f, 0.f,0.f,0.f,0.f, 0.f,0.f,0.f,0.f};
            f32x16 sT = __builtin_amdgcn_mfma_f32_32x32x16_bf16(kf, qf, z, 0, 0, 0);
            u32 pk[8];
            #pragma unroll
            for (int j = 0; j < 8; ++j) {
                float p0 = __expf(fminf(sT[2 * j], 80.f));
                float p1 = __expf(fminf(sT[2 * j + 1], 80.f));
                l_lane += p0 + p1;
                pk[j] = (u32)f2b(p0) | ((u32)f2b(p1) << 16);
            }
            #pragma unroll
            for (int s = 0; s < 2; ++s) {
                u32 s0 = hw ? pk[4 * s + 0] : pk[4 * s + 2];
                u32 s1 = hw ? pk[4 * s + 1] : pk[4 * s + 3];
                u32 r0 = __shfl_xor(s0, 32);
                u32 r1 = __shfl_xor(s1, 32);
                FragU pf;
                pf.u.x = hw ? r0 : pk[4 * s + 0];
                pf.u.y = hw ? r1 : pk[4 * s + 1];
                pf.u.z = hw ? pk[4 * s + 2] : r0;
                pf.u.w = hw ? pk[4 * s + 3] : r1;
                const u16* vsrc = base + (size_t)(32 + q5) * N_ + key0 + s * 16 + hw * 8;
                short8 vf = *(const short8*)vsrc;
                oacc = __builtin_amdgcn_mfma_f32_32x32x16_bf16(vf, pf.s, oacc, 0, 0, 0);
            }
        }
    }

    float l_q = l_lane + __shfl_xor(l_lane, 32);
    __syncthreads();   // all k_t/q_t reads done -> e-region reuse safe

    {   // write key-half partials: O (bf16) + l
        int qg = qt * 32 + q5;
        #pragma unroll
        for (int r = 0; r < 16; ++r) {
            int d = (r & 3) + 8 * (r >> 2) + 4 * hw;
            su.e.o_acc[kh][d][qg] = f2b(oacc[r]);
        }
        if (hw == 0) su.e.l_s[kh][qg] = l_q;
    }
    {   // stage v patch: image rows 2qb-1 .. 2qb+2, 32 d, zeros off-image
        int ybase = qb * 2 - 1;
        #pragma unroll
        for (int i = 0; i < 16; ++i) {
            int idx = i * 256 + t;
            int d = idx >> 7, px = idx & 127;
            int y = ybase + (px >> 5);
            float v = 0.f;
            if (y >= 0 && y < 32)
                v = b2f(base[(size_t)(32 + d) * N_ + y * 32 + (px & 31)]);
            su.e.v_pe[px][d] = v;
        }
    }
    __syncthreads();

    {   // combine partials + pe conv + transposed bf16 store
        int d = t & 31, pxg = t >> 5;        // 8 pixel-groups of 8
        int c = h * 32 + d;
        float w9[9];
        #pragma unroll
        for (int k = 0; k < 9; ++k) w9[k] = wpe_s[d][k];
        float beta = wpe_s[d][9];
        #pragma unroll
        for (int ii = 0; ii < 8; ++ii) {
            int pl = pxg * 8 + ii;           // 0..63 local pixel
            int xx0 = pl & 31;
            float s = beta;
            #pragma unroll
            for (int dy = -1; dy <= 1; ++dy) {
                #pragma unroll
                for (int dx = -1; dx <= 1; ++dx) {
                    int xx = xx0 + dx;
                    if (xx < 0 || xx > 31) continue;
                    s += w9[(dy + 1) * 3 + (dx + 1)] * su.e.v_pe[pl + 32 + dy * 32 + dx][d];
                }
            }
            float o = b2f(su.e.o_acc[0][d][pl]) + b2f(su.e.o_acc[1][d][pl]);
            float l = su.e.l_s[0][pl] + su.e.l_s[1][pl];
            xattnT[(size_t)(b * N_ + q0g + pl) * DIM_ + c] = f2b(o / fmaxf(l, 1e-30f) + s);
        }
    }
}

// ============ Kernel 3: out = BN(proj_w @ xattn) fp32, MFMA ============
// BN folded in prologue; fp32 weights converted on the fly; B-frags b128
// from xattnT. Block 64o x 64n; grid = 8b x 4ob x 16nb = 512.
__global__ __launch_bounds__(256) void k_proj(
    const u16* __restrict__ xattnT, const float* __restrict__ pw,
    const float* __restrict__ pg, const float* __restrict__ pb,
    const float* __restrict__ pm, const float* __restrict__ pv,
    float* __restrict__ out)
{
    __shared__ float2 bn_s[64];
    int blk = blockIdx.x;
    int nb = blk & 15, ob = (blk >> 4) & 3, b = blk >> 6;
    int t = threadIdx.x;
    int wv_ = t >> 6, lane = t & 63, quad = lane >> 4, l16 = lane & 15;
    int o_base = ob * 64 + (wv_ & 1) * 32;
    int n_base = nb * 64 + (wv_ >> 1) * 32;

    if (t < 64) {
        int o = ob * 64 + t;
        float inv = pg[o] / sqrtf(pv[o] + EPS_);
        bn_s[t] = make_float2(inv, pb[o] - pm[o] * inv);
    }
    __syncthreads();

    f32x4 acc[2][2];
    #pragma unroll
    for (int ot = 0; ot < 2; ++ot)
        #pragma unroll
        for (int nt = 0; nt < 2; ++nt) acc[ot][nt] = (f32x4){0.f, 0.f, 0.f, 0.f};

    const u16* xb = xattnT + (size_t)b * N_ * DIM_;
    for (int c0 = 0; c0 < DIM_; c0 += 32) {
        short8 af[2];
        #pragma unroll
        for (int ot = 0; ot < 2; ++ot)
            af[ot] = cvt8(pw + (size_t)(o_base + ot * 16 + l16) * DIM_ + c0 + quad * 8);
        short8 bf[2];
        #pragma unroll
        for (int nt = 0; nt < 2; ++nt)
            bf[nt] = *(const short8*)(xb + (size_t)(n_base + nt * 16 + l16) * DIM_ + c0 + quad * 8);
        #pragma unroll
        for (int ot = 0; ot < 2; ++ot)
            #pragma unroll
            for (int nt = 0; nt < 2; ++nt)
                acc[ot][nt] = __builtin_amdgcn_mfma_f32_16x16x32_bf16(af[ot], bf[nt], acc[ot][nt], 0, 0, 0);
    }
    #pragma unroll
    for (int ot = 0; ot < 2; ++ot)
        #pragma unroll
        for (int r = 0; r < 4; ++r) {
            int ol = (wv_ & 1) * 32 + ot * 16 + quad * 4 + r;
            float2 ib = bn_s[ol];
            float* dst = out + (size_t)(b * DIM_ + ob * 64 + ol) * N_ + n_base + l16;
            #pragma unroll
            for (int nt = 0; nt < 2; ++nt)
                dst[nt * 16] = acc[ot][nt][r] * ib.x + ib.y;
        }
}

extern "C" void kernel_launch(void* const* d_in, const int* in_sizes, int n_in,
                              void* d_out, int out_size, void* d_ws, size_t ws_size,
                              hipStream_t stream)
{
    const float* x      = (const float*)d_in[0];
    const float* qkv_w  = (const float*)d_in[1];
    const float* qkv_g  = (const float*)d_in[2];
    const float* qkv_b  = (const float*)d_in[3];
    const float* qkv_m  = (const float*)d_in[4];
    const float* qkv_v  = (const float*)d_in[5];
    const float* pe_w   = (const float*)d_in[6];
    const float* pe_g   = (const float*)d_in[7];
    const float* pe_b   = (const float*)d_in[8];
    const float* pe_m   = (const float*)d_in[9];
    const float* pe_v   = (const float*)d_in[10];
    const float* proj_w = (const float*)d_in[11];
    const float* proj_g = (const float*)d_in[12];
    const float* proj_b = (const float*)d_in[13];
    const float* proj_m = (const float*)d_in[14];
    const float* proj_v = (const float*)d_in[15];
    float* out = (float*)d_out;

    // ws: qkv bf16 (8 MB) + xattnT bf16 (4 MB)
    char* p = (char*)d_ws;
    u16* qkv    = (u16*)p;  p += (size_t)B_ * HOUT_ * N_ * sizeof(u16);
    u16* xattnT = (u16*)p;

    hipLaunchKernelGGL(k_qkv, dim3(512), dim3(256), 0, stream,
                       x, qkv_w, qkv_g, qkv_b, qkv_m, qkv_v, qkv);
    hipLaunchKernelGGL(k_attn, dim3(1024), dim3(256), 0, stream,
                       qkv, pe_w, pe_g, pe_b, pe_m, pe_v, xattnT);
    hipLaunchKernelGGL(k_proj, dim3(512), dim3(256), 0, stream,
                       xattnT, proj_w, proj_g, proj_b, proj_m, proj_v, out);
}

// Round 12
// 146.134 us; speedup vs baseline: 1.0488x; 1.0488x over previous
//
#include <hip/hip_runtime.h>
#include <hip/hip_bf16.h>

#define B_    8
#define DIM_  256
#define NH_   8
#define HD_   32
#define KD_   16
#define HOUT_ 512
#define N_    1024
#define SCALE_ 0.25f
#define EPS_  1e-3f

typedef unsigned short u16;
typedef unsigned int   u32;
typedef __attribute__((ext_vector_type(8)))  short short8;   // 8 bf16 (4 VGPR)
typedef __attribute__((ext_vector_type(4)))  float f32x4;
typedef __attribute__((ext_vector_type(16))) float f32x16;

union H4 { uint2 u; u16 e[4]; };
union FragU { uint4 u; short8 s; };
union F8 { short8 s; u16 e[8]; };

__device__ __forceinline__ float b2f(u16 u) {
    union { unsigned int i; float f; } c;
    c.i = ((unsigned int)u) << 16;
    return c.f;
}

__device__ __forceinline__ u16 f2b(float f) {
    union { float f; unsigned int i; } c;
    c.f = f;
    unsigned int x = c.i;
    return (u16)((x + 0x7fffu + ((x >> 16) & 1u)) >> 16);  // RNE
}

// 8 contiguous fp32 -> bf16 frag
__device__ __forceinline__ short8 cvt8(const float* p) {
    float4 a = ((const float4*)p)[0];
    float4 b = ((const float4*)p)[1];
    F8 f;
    f.e[0] = f2b(a.x); f.e[1] = f2b(a.y); f.e[2] = f2b(a.z); f.e[3] = f2b(a.w);
    f.e[4] = f2b(b.x); f.e[5] = f2b(b.y); f.e[6] = f2b(b.z); f.e[7] = f2b(b.w);
    return f.s;
}

// ============ Kernel 1: qkv = BN(qkv_w @ x) -> bf16 [o][n], MFMA ============
// LDS-staged x: bf16 [n][c], 40-u16 rows (80 B: 16B-aligned b128, 2-way max
// on frag reads). Staging = 16 lane-coalesced dwords + 2 b128 LDS writes per
// thread per K-step; B-frags = single b128 LDS reads shared block-wide.
// BN folded in prologue (q channels pre-scaled by 0.25). Block 64o x 128n,
// grid = 8b x 8ob x 8nb = 512.
__global__ __launch_bounds__(256) void k_qkv(
    const float* __restrict__ x, const float* __restrict__ qw,
    const float* __restrict__ qg, const float* __restrict__ qb,
    const float* __restrict__ qm, const float* __restrict__ qv,
    u16* __restrict__ qkv)
{
    __shared__ u16 x_s[128][40];   // [n][c0..c0+31] + 8 pad, 10 KB
    __shared__ float2 bn_s[64];
    int blk = blockIdx.x;
    int nb = blk & 7, ob = (blk >> 3) & 7, b = blk >> 6;
    int t = threadIdx.x;
    int wv_ = t >> 6, lane = t & 63, quad = lane >> 4, l16 = lane & 15;
    int o_base = ob * 64 + (wv_ & 1) * 32;
    int nw = (wv_ >> 1) * 64;

    if (t < 64) {
        int o = ob * 64 + t;
        float inv  = qg[o] / sqrtf(qv[o] + EPS_);
        float beta = qb[o] - qm[o] * inv;
        if (t < 16) { inv *= SCALE_; beta *= SCALE_; }   // q channels pre-scaled
        bn_s[t] = make_float2(inv, beta);
    }

    f32x4 acc[2][4];
    #pragma unroll
    for (int ot = 0; ot < 2; ++ot)
        #pragma unroll
        for (int nt = 0; nt < 4; ++nt) acc[ot][nt] = (f32x4){0.f, 0.f, 0.f, 0.f};

    const float* xb = x + (size_t)b * DIM_ * N_ + nb * 128;
    int sn = t & 127;              // staging n index
    int sc = (t >> 7) * 16;        // staging c offset (0 or 16)

    for (int c0 = 0; c0 < DIM_; c0 += 32) {
        short8 af[2];
        #pragma unroll
        for (int ot = 0; ot < 2; ++ot)
            af[ot] = cvt8(qw + (size_t)(o_base + ot * 16 + l16) * DIM_ + c0 + quad * 8);
        __syncthreads();           // previous-iteration x_s reads done
        {
            u16 tmp[16];
            #pragma unroll
            for (int j = 0; j < 16; ++j)
                tmp[j] = f2b(xb[(size_t)(c0 + sc + j) * N_ + sn]);
            *(uint4*)&x_s[sn][sc]     = *(uint4*)&tmp[0];
            *(uint4*)&x_s[sn][sc + 8] = *(uint4*)&tmp[8];
        }
        __syncthreads();
        short8 bf[4];
        #pragma unroll
        for (int nt = 0; nt < 4; ++nt)
            bf[nt] = *(const short8*)&x_s[nw + nt * 16 + l16][quad * 8];
        #pragma unroll
        for (int ot = 0; ot < 2; ++ot)
            #pragma unroll
            for (int nt = 0; nt < 4; ++nt)
                acc[ot][nt] = __builtin_amdgcn_mfma_f32_16x16x32_bf16(af[ot], bf[nt], acc[ot][nt], 0, 0, 0);
    }
    #pragma unroll
    for (int ot = 0; ot < 2; ++ot)
        #pragma unroll
        for (int r = 0; r < 4; ++r) {
            int ol = (wv_ & 1) * 32 + ot * 16 + quad * 4 + r;
            float2 ib = bn_s[ol];
            u16* dst = qkv + (size_t)(b * HOUT_ + ob * 64 + ol) * N_ + nb * 128 + nw + l16;
            #pragma unroll
            for (int nt = 0; nt < 4; ++nt)
                dst[nt * 16] = f2b(acc[ot][nt][r] * ib.x + ib.y);
        }
}

// ============ Kernel 2: flash attention, 32x32x16 MFMA, register-P, key-split ============
// R10/R11-verified structure. Per block: 64 q. Waves (kh=wv>>1, qt=wv&1).
// S^T = mfma_32x32x16(K, Q') (q pre-scaled in k_qkv); shfl_xor(32) pair
// exchange -> PV B-operand; PV A=V b128 global. pe taps BN-folded in prologue.
struct MainS { u16 q_t[64][24]; u16 k_t[2][256][24]; };
struct EpiS  { u16 o_acc[2][32][66]; float l_s[2][64]; float v_pe[128][33]; };
union  SmemU { MainS m; EpiS e; };

__global__ __launch_bounds__(256, 4) void k_attn(
    const u16* __restrict__ qkv, const float* __restrict__ pew,
    const float* __restrict__ eg, const float* __restrict__ eb,
    const float* __restrict__ em, const float* __restrict__ ev,
    u16* __restrict__ xattnT)
{
    __shared__ SmemU su;
    __shared__ float wpe_s[32][10];
    int blk = blockIdx.x;
    int qb = blk & 15;
    int h  = (blk >> 4) & 7;
    int b  = blk >> 7;
    int t    = threadIdx.x;
    int wv_  = t >> 6;
    int lane = t & 63;
    int q5   = lane & 31;
    int hw   = lane >> 5;
    int kh   = wv_ >> 1;
    int qt   = wv_ & 1;
    const u16* base = qkv + (size_t)(b * HOUT_ + h * 64) * N_;  // q':d, k:16+d, v:32+d
    int q0g = qb * 64;

    if (t < 32) {   // fold pe BN into taps
        int c = h * 32 + t;
        float inv = eg[c] / sqrtf(ev[c] + EPS_);
        #pragma unroll
        for (int k = 0; k < 9; ++k) wpe_s[t][k] = pew[c * 9 + k] * inv;
        wpe_s[t][9] = eb[c] - em[c] * inv;
    }
    {   // stage 64 q transposed (pure u16 copy — scale pre-folded)
        int q = t & 63, d4 = (t >> 6) * 4;
        H4 hh;
        #pragma unroll
        for (int i = 0; i < 4; ++i)
            hh.e[i] = base[(size_t)(d4 + i) * N_ + q0g + q];
        *(uint2*)&su.m.q_t[q][d4] = hh.u;
    }
    __syncthreads();

    short8 qf = *(const short8*)&su.m.q_t[qt * 32 + q5][hw * 8];

    f32x16 oacc = {0.f,0.f,0.f,0.f, 0.f,0.f,0.f,0.f, 0.f,0.f,0.f,0.f, 0.f,0.f,0.f,0.f};
    float l_lane = 0.f;

    for (int ch = 0; ch < 2; ++ch) {
        __syncthreads();
        {   // stage 512 keys (both halves), lane = key, conflict-free
            #pragma unroll
            for (int s2 = 0; s2 < 2; ++s2) {
                int key = s2 * 512 + ch * 256 + t;
                #pragma unroll
                for (int d4 = 0; d4 < 16; d4 += 4) {
                    H4 hh;
                    #pragma unroll
                    for (int i = 0; i < 4; ++i)
                        hh.e[i] = base[(size_t)(16 + d4 + i) * N_ + key];
                    *(uint2*)&su.m.k_t[s2][t][d4] = hh.u;
                }
            }
        }
        __syncthreads();

        #pragma unroll 2
        for (int tile = 0; tile < 8; ++tile) {
            int key0 = kh * 512 + ch * 256 + tile * 32;
            short8 kf = *(const short8*)&su.m.k_t[kh][tile * 32 + q5][hw * 8];
            f32x16 z = {0.f,0.f,0.f,0.f, 0.f,0.f,0.f,0.f, 0.f,0.f,0.f,0.f, 0.f,0.f,0.f,0.f};
            f32x16 sT = __builtin_amdgcn_mfma_f32_32x32x16_bf16(kf, qf, z, 0, 0, 0);
            u32 pk[8];
            #pragma unroll
            for (int j = 0; j < 8; ++j) {
                float p0 = __expf(fminf(sT[2 * j], 80.f));
                float p1 = __expf(fminf(sT[2 * j + 1], 80.f));
                l_lane += p0 + p1;
                pk[j] = (u32)f2b(p0) | ((u32)f2b(p1) << 16);
            }
            #pragma unroll
            for (int s = 0; s < 2; ++s) {
                u32 s0 = hw ? pk[4 * s + 0] : pk[4 * s + 2];
                u32 s1 = hw ? pk[4 * s + 1] : pk[4 * s + 3];
                u32 r0 = __shfl_xor(s0, 32);
                u32 r1 = __shfl_xor(s1, 32);
                FragU pf;
                pf.u.x = hw ? r0 : pk[4 * s + 0];
                pf.u.y = hw ? r1 : pk[4 * s + 1];
                pf.u.z = hw ? pk[4 * s + 2] : r0;
                pf.u.w = hw ? pk[4 * s + 3] : r1;
                const u16* vsrc = base + (size_t)(32 + q5) * N_ + key0 + s * 16 + hw * 8;
                short8 vf = *(const short8*)vsrc;
                oacc = __builtin_amdgcn_mfma_f32_32x32x16_bf16(vf, pf.s, oacc, 0, 0, 0);
            }
        }
    }

    float l_q = l_lane + __shfl_xor(l_lane, 32);
    __syncthreads();   // all k_t/q_t reads done -> e-region reuse safe

    {   // write key-half partials: O (bf16) + l
        int qg = qt * 32 + q5;
        #pragma unroll
        for (int r = 0; r < 16; ++r) {
            int d = (r & 3) + 8 * (r >> 2) + 4 * hw;
            su.e.o_acc[kh][d][qg] = f2b(oacc[r]);
        }
        if (hw == 0) su.e.l_s[kh][qg] = l_q;
    }
    {   // stage v patch: image rows 2qb-1 .. 2qb+2, 32 d, zeros off-image
        int ybase = qb * 2 - 1;
        #pragma unroll
        for (int i = 0; i < 16; ++i) {
            int idx = i * 256 + t;
            int d = idx >> 7, px = idx & 127;
            int y = ybase + (px >> 5);
            float v = 0.f;
            if (y >= 0 && y < 32)
                v = b2f(base[(size_t)(32 + d) * N_ + y * 32 + (px & 31)]);
            su.e.v_pe[px][d] = v;
        }
    }
    __syncthreads();

    {   // combine partials + pe conv + transposed bf16 store
        int d = t & 31, pxg = t >> 5;
        float w9[9];
        #pragma unroll
        for (int k = 0; k < 9; ++k) w9[k] = wpe_s[d][k];
        float beta = wpe_s[d][9];
        int c = h * 32 + d;
        #pragma unroll
        for (int ii = 0; ii < 8; ++ii) {
            int pl = pxg * 8 + ii;
            int xx0 = pl & 31;
            float s = beta;
            #pragma unroll
            for (int dy = -1; dy <= 1; ++dy) {
                #pragma unroll
                for (int dx = -1; dx <= 1; ++dx) {
                    int xx = xx0 + dx;
                    if (xx < 0 || xx > 31) continue;
                    s += w9[(dy + 1) * 3 + (dx + 1)] * su.e.v_pe[pl + 32 + dy * 32 + dx][d];
                }
            }
            float o = b2f(su.e.o_acc[0][d][pl]) + b2f(su.e.o_acc[1][d][pl]);
            float l = su.e.l_s[0][pl] + su.e.l_s[1][pl];
            xattnT[(size_t)(b * N_ + q0g + pl) * DIM_ + c] = f2b(o / fmaxf(l, 1e-30f) + s);
        }
    }
}

// ============ Kernel 3: out = BN(proj_w @ xattn) fp32, MFMA ============
// BN folded in prologue; fp32 weights converted on the fly; B-frags b128
// from xattnT. Block 64o x 64n; grid = 8b x 4ob x 16nb = 512.
__global__ __launch_bounds__(256) void k_proj(
    const u16* __restrict__ xattnT, const float* __restrict__ pw,
    const float* __restrict__ pg, const float* __restrict__ pb,
    const float* __restrict__ pm, const float* __restrict__ pv,
    float* __restrict__ out)
{
    __shared__ float2 bn_s[64];
    int blk = blockIdx.x;
    int nb = blk & 15, ob = (blk >> 4) & 3, b = blk >> 6;
    int t = threadIdx.x;
    int wv_ = t >> 6, lane = t & 63, quad = lane >> 4, l16 = lane & 15;
    int o_base = ob * 64 + (wv_ & 1) * 32;
    int n_base = nb * 64 + (wv_ >> 1) * 32;

    if (t < 64) {
        int o = ob * 64 + t;
        float inv = pg[o] / sqrtf(pv[o] + EPS_);
        bn_s[t] = make_float2(inv, pb[o] - pm[o] * inv);
    }
    __syncthreads();

    f32x4 acc[2][2];
    #pragma unroll
    for (int ot = 0; ot < 2; ++ot)
        #pragma unroll
        for (int nt = 0; nt < 2; ++nt) acc[ot][nt] = (f32x4){0.f, 0.f, 0.f, 0.f};

    const u16* xb = xattnT + (size_t)b * N_ * DIM_;
    for (int c0 = 0; c0 < DIM_; c0 += 32) {
        short8 af[2];
        #pragma unroll
        for (int ot = 0; ot < 2; ++ot)
            af[ot] = cvt8(pw + (size_t)(o_base + ot * 16 + l16) * DIM_ + c0 + quad * 8);
        short8 bf[2];
        #pragma unroll
        for (int nt = 0; nt < 2; ++nt)
            bf[nt] = *(const short8*)(xb + (size_t)(n_base + nt * 16 + l16) * DIM_ + c0 + quad * 8);
        #pragma unroll
        for (int ot = 0; ot < 2; ++ot)
            #pragma unroll
            for (int nt = 0; nt < 2; ++nt)
                acc[ot][nt] = __builtin_amdgcn_mfma_f32_16x16x32_bf16(af[ot], bf[nt], acc[ot][nt], 0, 0, 0);
    }
    #pragma unroll
    for (int ot = 0; ot < 2; ++ot)
        #pragma unroll
        for (int r = 0; r < 4; ++r) {
            int ol = (wv_ & 1) * 32 + ot * 16 + quad * 4 + r;
            float2 ib = bn_s[ol];
            float* dst = out + (size_t)(b * DIM_ + ob * 64 + ol) * N_ + n_base + l16;
            #pragma unroll
            for (int nt = 0; nt < 2; ++nt)
                dst[nt * 16] = acc[ot][nt][r] * ib.x + ib.y;
        }
}

extern "C" void kernel_launch(void* const* d_in, const int* in_sizes, int n_in,
                              void* d_out, int out_size, void* d_ws, size_t ws_size,
                              hipStream_t stream)
{
    const float* x      = (const float*)d_in[0];
    const float* qkv_w  = (const float*)d_in[1];
    const float* qkv_g  = (const float*)d_in[2];
    const float* qkv_b  = (const float*)d_in[3];
    const float* qkv_m  = (const float*)d_in[4];
    const float* qkv_v  = (const float*)d_in[5];
    const float* pe_w   = (const float*)d_in[6];
    const float* pe_g   = (const float*)d_in[7];
    const float* pe_b   = (const float*)d_in[8];
    const float* pe_m   = (const float*)d_in[9];
    const float* pe_v   = (const float*)d_in[10];
    const float* proj_w = (const float*)d_in[11];
    const float* proj_g = (const float*)d_in[12];
    const float* proj_b = (const float*)d_in[13];
    const float* proj_m = (const float*)d_in[14];
    const float* proj_v = (const float*)d_in[15];
    float* out = (float*)d_out;

    // ws: qkv bf16 (8 MB) + xattnT bf16 (4 MB)
    char* p = (char*)d_ws;
    u16* qkv    = (u16*)p;  p += (size_t)B_ * HOUT_ * N_ * sizeof(u16);
    u16* xattnT = (u16*)p;

    hipLaunchKernelGGL(k_qkv, dim3(512), dim3(256), 0, stream,
                       x, qkv_w, qkv_g, qkv_b, qkv_m, qkv_v, qkv);
    hipLaunchKernelGGL(k_attn, dim3(1024), dim3(256), 0, stream,
                       qkv, pe_w, pe_g, pe_b, pe_m, pe_v, xattnT);
    hipLaunchKernelGGL(k_proj, dim3(512), dim3(256), 0, stream,
                       xattnT, proj_w, proj_g, proj_b, proj_m, proj_v, out);
}